// Round 13
// baseline (151.301 us; speedup 1.0000x reference)
//
#include <hip/hip_runtime.h>
#include <hip/hip_bf16.h>
#include <stdint.h>

typedef unsigned short u16;
typedef __attribute__((ext_vector_type(8))) short short8;
typedef __attribute__((ext_vector_type(4))) float f32x4;

// ---------- helpers ----------
__device__ __forceinline__ uint32_t f2bf(float f) {
    union { float f; uint32_t u; } c; c.f = f;
    uint32_t u = c.u;
    u += 0x7fffu + ((u >> 16) & 1u);   // round-to-nearest-even
    return u >> 16;
}

__device__ __forceinline__ void glds16(const void* g, void* l) {
    __builtin_amdgcn_global_load_lds(
        (const __attribute__((address_space(1))) uint32_t*)g,
        (__attribute__((address_space(3))) uint32_t*)l,
        16, 0, 0);
}

// ---------- kernel 1: g_p = FWHT_1024(D_p[:1024] * V) / 1024, for 4 params ----------
__global__ void fwht_g_kernel(const float* __restrict__ V,
                              const float* __restrict__ D0, const float* __restrict__ D1,
                              const float* __restrict__ D2, const float* __restrict__ D3,
                              float* __restrict__ g) {
    __shared__ float s[1024];
    int t = threadIdx.x;
    const float* D = (blockIdx.x == 0) ? D0 : (blockIdx.x == 1) ? D1 :
                     (blockIdx.x == 2) ? D2 : D3;
    s[t] = D[t] * V[t];
    __syncthreads();
    #pragma unroll
    for (int st = 512; st >= 1; st >>= 1) {
        float a = s[t];
        float b = s[t ^ st];
        __syncthreads();
        s[t] = (t & st) ? (b - a) : (a + b);
        __syncthreads();
    }
    g[blockIdx.x * 1024 + t] = s[t] * (1.0f / 1024.0f);
}

// ---------- kernel 2: bias = init + PP * g[i&1023] ----------
__global__ void bias_kernel(const float* __restrict__ init, const float* __restrict__ PP,
                            const float* __restrict__ g, float* __restrict__ out, int n) {
    int i = blockIdx.x * blockDim.x + threadIdx.x;
    if (i < n) out[i] = init[i] + PP[i] * g[i & 1023];
}

// ---------- kernel 3: f32 -> bf16 cast (x), 4 elems/thread ----------
__global__ void cast_kernel(const float* __restrict__ in, u16* __restrict__ out, int n4) {
    int i = blockIdx.x * blockDim.x + threadIdx.x;
    if (i >= n4) return;
    float4 v = ((const float4*)in)[i];
    uint32_t lo = f2bf(v.x) | (f2bf(v.y) << 16);
    uint32_t hi = f2bf(v.z) | (f2bf(v.w) << 16);
    ((uint2*)out)[i] = make_uint2(lo, hi);
}

// ---------- kernel 4: W_bf16 = bf16(W_init + PP * g[idx&1023]), 4 elems/thread ----------
__global__ void wmat_kernel(const float* __restrict__ init, const float* __restrict__ PP,
                            const float* __restrict__ g, u16* __restrict__ out, int n4) {
    int i = blockIdx.x * blockDim.x + threadIdx.x;
    if (i >= n4) return;
    int e = i * 4;
    float4 wi = ((const float4*)init)[i];
    float4 pp = ((const float4*)PP)[i];
    float4 gv = *((const float4*)(g + (e & 1023)));
    uint32_t lo = f2bf(wi.x + pp.x * gv.x) | (f2bf(wi.y + pp.y * gv.y) << 16);
    uint32_t hi = f2bf(wi.z + pp.z * gv.z) | (f2bf(wi.w + pp.w * gv.w) << 16);
    ((uint2*)out)[i] = make_uint2(lo, hi);
}

// ---------- kernel 5: split-K GEMM partial: P[s] = A(MxKs) @ B^T(NxKs) ----------
// BM=128, BN=128, BK=64 (r1-measured VGPR=88 shape), 32 KB LDS single-buffered.
// Grid (N/128, M/128, S=8) = 1024 WGs -> 4 WG/CU resident in ONE batch (the TLP
// that made r11 work) with 2x the MFMA per staged byte and half the barriers/WG.
// XOR swizzle both tiles (BANK_CONFLICT ~0, validated r9/r11).
// 4 waves 2x2: wave tile 64x64, acc[4][4] = 32 MFMA/wave/K-step.
__global__ __launch_bounds__(256, 4) void gemm_splitk(const u16* __restrict__ A,
                                                      const u16* __restrict__ B,
                                                      float* __restrict__ P,
                                                      int M, int N, int K, int Kslice) {
    constexpr int BM = 128, BN = 128, BK = 64;
    __shared__ u16 As[BM * BK];   // 16 KB
    __shared__ u16 Bs[BN * BK];   // 16 KB

    const int t    = threadIdx.x;
    const int wid  = t >> 6;
    const int lane = t & 63;
    const int wr   = wid >> 1;        // 0..1: 64-row block of A
    const int wc   = wid & 1;         // 0..1: 64-col block of B
    const int fr   = lane & 15;
    const int fq   = lane >> 4;
    const int rx   = (fr & 7) << 4;   // read-side swizzle xor (bytes)

    const int bn = blockIdx.x, bm = blockIdx.y, sk = blockIdx.z;
    const int k_beg = sk * Kslice;

    const u16* Abase = A + (size_t)(bm * BM) * K;
    const u16* Bbase = B + (size_t)(bn * BN) * K;

    f32x4 acc[4][4];
    #pragma unroll
    for (int m = 0; m < 4; ++m)
        #pragma unroll
        for (int n = 0; n < 4; ++n)
            acc[m][n] = (f32x4){0.f, 0.f, 0.f, 0.f};

    #pragma unroll 1
    for (int k0 = k_beg; k0 < k_beg + Kslice; k0 += BK) {
        // stage A: 128x64 = 1024 16B-chunks = 4 rounds; source col pre-swizzled
        #pragma unroll
        for (int q = 0; q < 4; ++q) {
            int L = q * 256 + t;
            int row = L >> 3;
            int cg  = (L & 7) ^ (row & 7);
            glds16(Abase + (size_t)row * K + k0 + cg * 8, As + L * 8);
        }
        // stage B: 128x64 = 1024 chunks = 4 rounds
        #pragma unroll
        for (int q = 0; q < 4; ++q) {
            int L = q * 256 + t;
            int row = L >> 3;
            int cg  = (L & 7) ^ (row & 7);
            glds16(Bbase + (size_t)row * K + k0 + cg * 8, Bs + L * 8);
        }
        __syncthreads();

        const char* Ap = (const char*)As;
        const char* Bp = (const char*)Bs;
        __builtin_amdgcn_s_setprio(1);
        #pragma unroll
        for (int ks = 0; ks < 2; ++ks) {
            const int co = (ks * 64 + fq * 16) ^ rx;
            short8 a[4], b[4];
            #pragma unroll
            for (int m = 0; m < 4; ++m)
                a[m] = *(const short8*)(Ap + (wr * 64 + m * 16 + fr) * 128 + co);
            #pragma unroll
            for (int n = 0; n < 4; ++n)
                b[n] = *(const short8*)(Bp + (wc * 64 + n * 16 + fr) * 128 + co);
            #pragma unroll
            for (int m = 0; m < 4; ++m)
                #pragma unroll
                for (int n = 0; n < 4; ++n)
                    acc[m][n] = __builtin_amdgcn_mfma_f32_16x16x32_bf16(a[m], b[n], acc[m][n], 0, 0, 0);
        }
        __builtin_amdgcn_s_setprio(0);
        __syncthreads();
    }

    // epilogue: write f32 partial tile
    float* Pp = P + (size_t)sk * M * N;
    #pragma unroll
    for (int m = 0; m < 4; ++m) {
        int grow0 = bm * BM + wr * 64 + m * 16 + fq * 4;
        #pragma unroll
        for (int n = 0; n < 4; ++n) {
            int gcol = bn * BN + wc * 64 + n * 16 + fr;
            #pragma unroll
            for (int j = 0; j < 4; ++j)
                Pp[(size_t)(grow0 + j) * N + gcol] = acc[m][n][j];
        }
    }
}

// ---------- kernel 6: reduce S partials + bias (+relu) -> bf16 or f32 ----------
template <typename OutT, bool RELU, int S>
__global__ void reduce_kernel(const float* __restrict__ P, const float* __restrict__ bias,
                              OutT* __restrict__ out, int MN, int N) {
    int i = blockIdx.x * blockDim.x + threadIdx.x;   // handles 4 elems
    if (i * 4 >= MN) return;
    int e = i * 4;
    int col = e & (N - 1);
    float4 acc = ((const float4*)(P + e))[0];
    #pragma unroll
    for (int s = 1; s < S; ++s) {
        float4 p = ((const float4*)(P + (size_t)s * MN + e))[0];
        acc.x += p.x; acc.y += p.y; acc.z += p.z; acc.w += p.w;
    }
    float4 bv = *((const float4*)(bias + col));
    acc.x += bv.x; acc.y += bv.y; acc.z += bv.z; acc.w += bv.w;
    if (RELU) {
        acc.x = fmaxf(acc.x, 0.f); acc.y = fmaxf(acc.y, 0.f);
        acc.z = fmaxf(acc.z, 0.f); acc.w = fmaxf(acc.w, 0.f);
    }
    if constexpr (sizeof(OutT) == 2) {
        uint32_t lo = f2bf(acc.x) | (f2bf(acc.y) << 16);
        uint32_t hi = f2bf(acc.z) | (f2bf(acc.w) << 16);
        ((uint2*)out)[i] = make_uint2(lo, hi);
    } else {
        ((float4*)out)[i] = acc;
    }
}

// ---------- launch ----------
extern "C" void kernel_launch(void* const* d_in, const int* in_sizes, int n_in,
                              void* d_out, int out_size, void* d_ws, size_t ws_size,
                              hipStream_t stream) {
    (void)in_sizes; (void)n_in; (void)out_size; (void)ws_size;

    const float* x       = (const float*)d_in[0];
    const float* V       = (const float*)d_in[1];
    const float* W1_init = (const float*)d_in[2];
    const float* D_W1    = (const float*)d_in[3];
    const float* PP_W1   = (const float*)d_in[4];
    const float* b1_init = (const float*)d_in[5];
    const float* D_b1    = (const float*)d_in[6];
    const float* PP_b1   = (const float*)d_in[7];
    const float* W2_init = (const float*)d_in[8];
    const float* D_W2    = (const float*)d_in[9];
    const float* PP_W2   = (const float*)d_in[10];
    const float* b2_init = (const float*)d_in[11];
    const float* D_b2    = (const float*)d_in[12];
    const float* PP_b2   = (const float*)d_in[13];

    constexpr size_t MB = 1024 * 1024;
    char* ws = (char*)d_ws;
    float* g    = (float*)(ws);                      // 4x1024 f32: [W1 | b1 | W2 | b2]
    float* b1w  = (float*)(ws + 16384);              // 4096 f32
    float* b2w  = (float*)(ws + 32768);              // 4096 f32
    u16*   xb   = (u16*)(ws + 65536);                // 512x4096 bf16 (4 MB)
    u16*   hb   = (u16*)(ws + 65536 + 4 * MB);       // 512x4096 bf16 (4 MB)
    u16*   wbuf = (u16*)(ws + 65536 + 8 * MB);       // 32 MB: W1 then W2
    float* Pbuf = (float*)(ws + 65536 + 40 * MB);    // 8x512x4096 f32 (64 MB)

    const int M = 512, N = 4096, K = 4096, S = 8, Kslice = K / S;

    fwht_g_kernel<<<4, 1024, 0, stream>>>(V, D_W1, D_b1, D_W2, D_b2, g);
    bias_kernel<<<4, 1024, 0, stream>>>(b1_init, PP_b1, g + 1024, b1w, 4096);
    bias_kernel<<<4, 1024, 0, stream>>>(b2_init, PP_b2, g + 3072, b2w, 4096);
    cast_kernel<<<2048, 256, 0, stream>>>(x, xb, M * K / 4);

    // layer 1: materialize W1, GEMM (1024 WGs, 4 WG/CU, dense tile), reduce
    wmat_kernel<<<16384, 256, 0, stream>>>(W1_init, PP_W1, g, wbuf, 4096 * 4096 / 4);
    gemm_splitk<<<dim3(N / 128, M / 128, S), 256, 0, stream>>>(xb, wbuf, Pbuf, M, N, K, Kslice);
    reduce_kernel<u16, true, S><<<M * N / 4 / 256, 256, 0, stream>>>(Pbuf, b1w, hb, M * N, N);

    // layer 2 (wbuf, Pbuf reused)
    wmat_kernel<<<16384, 256, 0, stream>>>(W2_init, PP_W2, g + 2048, wbuf, 4096 * 4096 / 4);
    gemm_splitk<<<dim3(N / 128, M / 128, S), 256, 0, stream>>>(hb, wbuf, Pbuf, M, N, K, Kslice);
    reduce_kernel<float, false, S><<<M * N / 4 / 256, 256, 0, stream>>>(Pbuf, b2w, (float*)d_out, M * N, N);
}

// Round 14
// 129.260 us; speedup vs baseline: 1.1705x; 1.1705x over previous
//
#include <hip/hip_runtime.h>
#include <hip/hip_bf16.h>
#include <stdint.h>

typedef unsigned short u16;
typedef __attribute__((ext_vector_type(8))) short short8;
typedef __attribute__((ext_vector_type(4))) float f32x4;

// ---------- helpers ----------
__device__ __forceinline__ uint32_t f2bf(float f) {
    union { float f; uint32_t u; } c; c.f = f;
    uint32_t u = c.u;
    u += 0x7fffu + ((u >> 16) & 1u);   // round-to-nearest-even
    return u >> 16;
}

__device__ __forceinline__ float bf2f(uint32_t u) {
    union { uint32_t u; float f; } c; c.u = u << 16; return c.f;
}

__device__ __forceinline__ void glds16(const void* g, void* l) {
    __builtin_amdgcn_global_load_lds(
        (const __attribute__((address_space(1))) uint32_t*)g,
        (__attribute__((address_space(3))) uint32_t*)l,
        16, 0, 0);
}

// ---------- kernel 1: g_p = FWHT_1024(D_p[:1024] * V) / 1024, for 4 params ----------
__global__ void fwht_g_kernel(const float* __restrict__ V,
                              const float* __restrict__ D0, const float* __restrict__ D1,
                              const float* __restrict__ D2, const float* __restrict__ D3,
                              float* __restrict__ g) {
    __shared__ float s[1024];
    int t = threadIdx.x;
    const float* D = (blockIdx.x == 0) ? D0 : (blockIdx.x == 1) ? D1 :
                     (blockIdx.x == 2) ? D2 : D3;
    s[t] = D[t] * V[t];
    __syncthreads();
    #pragma unroll
    for (int st = 512; st >= 1; st >>= 1) {
        float a = s[t];
        float b = s[t ^ st];
        __syncthreads();
        s[t] = (t & st) ? (b - a) : (a + b);
        __syncthreads();
    }
    g[blockIdx.x * 1024 + t] = s[t] * (1.0f / 1024.0f);
}

// ---------- kernel 2: bias = init + PP * g[i&1023] ----------
__global__ void bias_kernel(const float* __restrict__ init, const float* __restrict__ PP,
                            const float* __restrict__ g, float* __restrict__ out, int n) {
    int i = blockIdx.x * blockDim.x + threadIdx.x;
    if (i < n) out[i] = init[i] + PP[i] * g[i & 1023];
}

// ---------- kernel 3: f32 -> bf16 cast (x), 4 elems/thread ----------
__global__ void cast_kernel(const float* __restrict__ in, u16* __restrict__ out, int n4) {
    int i = blockIdx.x * blockDim.x + threadIdx.x;
    if (i >= n4) return;
    float4 v = ((const float4*)in)[i];
    uint32_t lo = f2bf(v.x) | (f2bf(v.y) << 16);
    uint32_t hi = f2bf(v.z) | (f2bf(v.w) << 16);
    ((uint2*)out)[i] = make_uint2(lo, hi);
}

// ---------- kernel 4: W_bf16 = bf16(W_init + PP * g[idx&1023]), 4 elems/thread ----------
__global__ void wmat_kernel(const float* __restrict__ init, const float* __restrict__ PP,
                            const float* __restrict__ g, u16* __restrict__ out, int n4) {
    int i = blockIdx.x * blockDim.x + threadIdx.x;
    if (i >= n4) return;
    int e = i * 4;
    float4 wi = ((const float4*)init)[i];
    float4 pp = ((const float4*)PP)[i];
    float4 gv = *((const float4*)(g + (e & 1023)));
    uint32_t lo = f2bf(wi.x + pp.x * gv.x) | (f2bf(wi.y + pp.y * gv.y) << 16);
    uint32_t hi = f2bf(wi.z + pp.z * gv.z) | (f2bf(wi.w + pp.w * gv.w) << 16);
    ((uint2*)out)[i] = make_uint2(lo, hi);
}

// ---------- kernel 5: split-K GEMM partial: P[s] = A(MxKs) @ B^T(NxKs), bf16 out ----------
// r11-proven config: BM=128, BN=64, BK=64, single-buffered 24 KB LDS,
// grid (N/64, M/128, 4) = 1024 WGs = 4 WG/CU, XOR swizzle both tiles.
// 4 waves 2x2: wave tile 64x32, acc[4][2]. Partials stored bf16 (halves P traffic).
__global__ __launch_bounds__(256, 4) void gemm_splitk(const u16* __restrict__ A,
                                                      const u16* __restrict__ B,
                                                      u16* __restrict__ P,
                                                      int M, int N, int K, int Kslice) {
    constexpr int BM = 128, BN = 64, BK = 64;
    __shared__ u16 As[BM * BK];   // 16 KB
    __shared__ u16 Bs[BN * BK];   // 8 KB

    const int t    = threadIdx.x;
    const int wid  = t >> 6;
    const int lane = t & 63;
    const int wr   = wid >> 1;        // 0..1: 64-row block of A
    const int wc   = wid & 1;         // 0..1: 32-col block of B
    const int fr   = lane & 15;
    const int fq   = lane >> 4;
    const int rx   = (fr & 7) << 4;   // read-side swizzle xor (bytes)

    const int bn = blockIdx.x, bm = blockIdx.y, sk = blockIdx.z;
    const int k_beg = sk * Kslice;

    const u16* Abase = A + (size_t)(bm * BM) * K;
    const u16* Bbase = B + (size_t)(bn * BN) * K;

    f32x4 acc[4][2];
    #pragma unroll
    for (int m = 0; m < 4; ++m)
        #pragma unroll
        for (int n = 0; n < 2; ++n)
            acc[m][n] = (f32x4){0.f, 0.f, 0.f, 0.f};

    #pragma unroll 1
    for (int k0 = k_beg; k0 < k_beg + Kslice; k0 += BK) {
        // stage A: 128x64 = 1024 16B-chunks = 4 rounds; source col pre-swizzled
        #pragma unroll
        for (int q = 0; q < 4; ++q) {
            int L = q * 256 + t;
            int row = L >> 3;
            int cg  = (L & 7) ^ (row & 7);
            glds16(Abase + (size_t)row * K + k0 + cg * 8, As + L * 8);
        }
        // stage B: 64x64 = 512 chunks = 2 rounds
        #pragma unroll
        for (int q = 0; q < 2; ++q) {
            int L = q * 256 + t;
            int row = L >> 3;
            int cg  = (L & 7) ^ (row & 7);
            glds16(Bbase + (size_t)row * K + k0 + cg * 8, Bs + L * 8);
        }
        __syncthreads();

        const char* Ap = (const char*)As;
        const char* Bp = (const char*)Bs;
        __builtin_amdgcn_s_setprio(1);
        #pragma unroll
        for (int ks = 0; ks < 2; ++ks) {
            const int co = (ks * 64 + fq * 16) ^ rx;
            short8 a[4], b[2];
            #pragma unroll
            for (int m = 0; m < 4; ++m)
                a[m] = *(const short8*)(Ap + (wr * 64 + m * 16 + fr) * 128 + co);
            #pragma unroll
            for (int n = 0; n < 2; ++n)
                b[n] = *(const short8*)(Bp + (wc * 32 + n * 16 + fr) * 128 + co);
            #pragma unroll
            for (int m = 0; m < 4; ++m)
                #pragma unroll
                for (int n = 0; n < 2; ++n)
                    acc[m][n] = __builtin_amdgcn_mfma_f32_16x16x32_bf16(a[m], b[n], acc[m][n], 0, 0, 0);
        }
        __builtin_amdgcn_s_setprio(0);
        __syncthreads();
    }

    // epilogue: write bf16 partial tile
    u16* Pp = P + (size_t)sk * M * N;
    #pragma unroll
    for (int m = 0; m < 4; ++m) {
        int grow0 = bm * BM + wr * 64 + m * 16 + fq * 4;
        #pragma unroll
        for (int n = 0; n < 2; ++n) {
            int gcol = bn * BN + wc * 32 + n * 16 + fr;
            #pragma unroll
            for (int j = 0; j < 4; ++j)
                Pp[(size_t)(grow0 + j) * N + gcol] = (u16)f2bf(acc[m][n][j]);
        }
    }
}

// ---------- kernel 6: reduce S bf16 partials + bias (+relu) -> bf16 or f32 ----------
// 8 elems/thread (uint4 = 8 bf16 per slice read).
template <typename OutT, bool RELU, int S>
__global__ void reduce_kernel(const u16* __restrict__ P, const float* __restrict__ bias,
                              OutT* __restrict__ out, int MN, int N) {
    int i = blockIdx.x * blockDim.x + threadIdx.x;   // handles 8 elems
    if (i * 8 >= MN) return;
    int e = i * 8;
    int col = e & (N - 1);

    float a0 = 0.f, a1 = 0.f, a2 = 0.f, a3 = 0.f, a4 = 0.f, a5 = 0.f, a6 = 0.f, a7 = 0.f;
    #pragma unroll
    for (int s = 0; s < S; ++s) {
        uint4 v = ((const uint4*)(P + (size_t)s * MN))[i];
        a0 += bf2f(v.x & 0xffffu);  a1 += bf2f(v.x >> 16);
        a2 += bf2f(v.y & 0xffffu);  a3 += bf2f(v.y >> 16);
        a4 += bf2f(v.z & 0xffffu);  a5 += bf2f(v.z >> 16);
        a6 += bf2f(v.w & 0xffffu);  a7 += bf2f(v.w >> 16);
    }
    float4 bv0 = ((const float4*)(bias + col))[0];
    float4 bv1 = ((const float4*)(bias + col))[1];
    a0 += bv0.x; a1 += bv0.y; a2 += bv0.z; a3 += bv0.w;
    a4 += bv1.x; a5 += bv1.y; a6 += bv1.z; a7 += bv1.w;
    if (RELU) {
        a0 = fmaxf(a0, 0.f); a1 = fmaxf(a1, 0.f); a2 = fmaxf(a2, 0.f); a3 = fmaxf(a3, 0.f);
        a4 = fmaxf(a4, 0.f); a5 = fmaxf(a5, 0.f); a6 = fmaxf(a6, 0.f); a7 = fmaxf(a7, 0.f);
    }
    if constexpr (sizeof(OutT) == 2) {
        uint4 r;
        r.x = f2bf(a0) | (f2bf(a1) << 16);
        r.y = f2bf(a2) | (f2bf(a3) << 16);
        r.z = f2bf(a4) | (f2bf(a5) << 16);
        r.w = f2bf(a6) | (f2bf(a7) << 16);
        ((uint4*)out)[i] = r;
    } else {
        float4 o0 = {a0, a1, a2, a3};
        float4 o1 = {a4, a5, a6, a7};
        ((float4*)out)[i * 2]     = o0;
        ((float4*)out)[i * 2 + 1] = o1;
    }
}

// ---------- launch ----------
extern "C" void kernel_launch(void* const* d_in, const int* in_sizes, int n_in,
                              void* d_out, int out_size, void* d_ws, size_t ws_size,
                              hipStream_t stream) {
    (void)in_sizes; (void)n_in; (void)out_size; (void)ws_size;

    const float* x       = (const float*)d_in[0];
    const float* V       = (const float*)d_in[1];
    const float* W1_init = (const float*)d_in[2];
    const float* D_W1    = (const float*)d_in[3];
    const float* PP_W1   = (const float*)d_in[4];
    const float* b1_init = (const float*)d_in[5];
    const float* D_b1    = (const float*)d_in[6];
    const float* PP_b1   = (const float*)d_in[7];
    const float* W2_init = (const float*)d_in[8];
    const float* D_W2    = (const float*)d_in[9];
    const float* PP_W2   = (const float*)d_in[10];
    const float* b2_init = (const float*)d_in[11];
    const float* D_b2    = (const float*)d_in[12];
    const float* PP_b2   = (const float*)d_in[13];

    constexpr size_t MB = 1024 * 1024;
    char* ws = (char*)d_ws;
    float* g    = (float*)(ws);                      // 4x1024 f32: [W1 | b1 | W2 | b2]
    float* b1w  = (float*)(ws + 16384);              // 4096 f32
    float* b2w  = (float*)(ws + 32768);              // 4096 f32
    u16*   xb   = (u16*)(ws + 65536);                // 512x4096 bf16 (4 MB)
    u16*   hb   = (u16*)(ws + 65536 + 4 * MB);       // 512x4096 bf16 (4 MB)
    u16*   wbuf = (u16*)(ws + 65536 + 8 * MB);       // 32 MB: W1 then W2
    u16*   Pbuf = (u16*)(ws + 65536 + 40 * MB);      // 4x512x4096 bf16 (16 MB)

    const int M = 512, N = 4096, K = 4096, S = 4, Kslice = K / S;

    fwht_g_kernel<<<4, 1024, 0, stream>>>(V, D_W1, D_b1, D_W2, D_b2, g);
    bias_kernel<<<4, 1024, 0, stream>>>(b1_init, PP_b1, g + 1024, b1w, 4096);
    bias_kernel<<<4, 1024, 0, stream>>>(b2_init, PP_b2, g + 3072, b2w, 4096);
    cast_kernel<<<2048, 256, 0, stream>>>(x, xb, M * K / 4);

    // layer 1: materialize W1, GEMM (1024 WGs = 4 WG/CU), reduce
    wmat_kernel<<<16384, 256, 0, stream>>>(W1_init, PP_W1, g, wbuf, 4096 * 4096 / 4);
    gemm_splitk<<<dim3(N / 64, M / 128, S), 256, 0, stream>>>(xb, wbuf, Pbuf, M, N, K, Kslice);
    reduce_kernel<u16, true, S><<<M * N / 8 / 256, 256, 0, stream>>>(Pbuf, b1w, hb, M * N, N);

    // layer 2 (wbuf, Pbuf reused)
    wmat_kernel<<<16384, 256, 0, stream>>>(W2_init, PP_W2, g + 2048, wbuf, 4096 * 4096 / 4);
    gemm_splitk<<<dim3(N / 64, M / 128, S), 256, 0, stream>>>(hb, wbuf, Pbuf, M, N, K, Kslice);
    reduce_kernel<float, false, S><<<M * N / 8 / 256, 256, 0, stream>>>(Pbuf, b2w, (float*)d_out, M * N, N);
}